// Round 1
// 510.095 us; speedup vs baseline: 1.7910x; 1.7910x over previous
//
#include <hip/hip_runtime.h>

#define Bc   64
#define Cc   256
#define Nn   2304
#define DFFf 512
#define Mm   64
#define NTILE 64
#define NTB   36   // 2304/64

typedef __bf16 bf16_t;
typedef __bf16 bf16x8 __attribute__((ext_vector_type(8)));
typedef __bf16 bf16x4 __attribute__((ext_vector_type(4)));
typedef float  f32x4  __attribute__((ext_vector_type(4)));

__device__ __forceinline__ bf16_t cvt(float f) { return (bf16_t)f; }

__device__ __forceinline__ f32x4 mfma16(bf16x8 a, bf16x8 b, f32x4 c) {
    return __builtin_amdgcn_mfma_f32_16x16x32_bf16(a, b, c, 0, 0, 0);
}

// ---------------------------------------------------------------------------
// K/V precompute (fp32): K[c][m] = wk[c,:]·bcw[m,:] + bk[c]   (unchanged)
// ---------------------------------------------------------------------------
__global__ void kv_kernel(const float* __restrict__ wk, const float* __restrict__ bk,
                          const float* __restrict__ wv, const float* __restrict__ bv,
                          const float* __restrict__ bcw,
                          float* __restrict__ Kout, float* __restrict__ Vout) {
    int c = blockIdx.x;      // 256
    int m = threadIdx.x;     // 64
    const float* wkr = wk + c * Cc;
    const float* wvr = wv + c * Cc;
    const float* br  = bcw + m * Cc;
    float aK = 0.f, aV = 0.f;
    #pragma unroll 8
    for (int i = 0; i < Cc; ++i) {
        float bcv = br[i];
        aK = fmaf(wkr[i], bcv, aK);
        aV = fmaf(wvr[i], bcv, aV);
    }
    Kout[c * Mm + m] = aK + bk[c];
    Vout[c * Mm + m] = aV + bv[c];
}

// ---------------------------------------------------------------------------
// Pack weights into MFMA A-fragment order (bf16).  (unchanged layouts)
// ---------------------------------------------------------------------------
__global__ void pack_kernel(const float* __restrict__ wq, const float* __restrict__ bq,
                            const float* __restrict__ wm, const float* __restrict__ w1,
                            const float* __restrict__ w2,
                            const float* __restrict__ Kf32, const float* __restrict__ Vf32,
                            bf16_t* __restrict__ wqf, bf16_t* __restrict__ wmf,
                            bf16_t* __restrict__ w1f, bf16_t* __restrict__ w2f,
                            bf16_t* __restrict__ Kf, bf16_t* __restrict__ Vf,
                            float* __restrict__ bqp) {
    int idx = blockIdx.x * 256 + threadIdx.x;
    if (idx < 65536) {                       // wqf: 16rt x 8ks, row-permuted
        int e = idx;
        int j = e & 7, lane = (e >> 3) & 63, rs = e >> 9;
        int ks = rs & 7, rt = rs >> 3;
        int op = rt * 16 + (lane & 15);           // hd = h*32+d
        int k  = ks * 32 + (lane >> 4) * 8 + j;
        int c  = (op & 31) * 8 + (op >> 5);       // c = d*8+h
        wqf[e] = cvt(wq[c * 256 + k]);
    } else if (idx < 131072) {               // wmf: col-permuted
        int e = idx - 65536;
        int j = e & 7, lane = (e >> 3) & 63, rs = e >> 9;
        int ks = rs & 7, rt = rs >> 3;
        int o = rt * 16 + (lane & 15);
        int k = ks * 32 + (lane >> 4) * 8 + j;    // hd
        int c = (k & 31) * 8 + (k >> 5);
        wmf[e] = cvt(wm[o * 256 + c]);
    } else if (idx < 262144) {               // w1f: 32rt x 8ks plain
        int e = idx - 131072;
        int j = e & 7, lane = (e >> 3) & 63, rs = e >> 9;
        int ks = rs & 7, rt = rs >> 3;
        w1f[e] = cvt(w1[(rt * 16 + (lane & 15)) * 256 + ks * 32 + (lane >> 4) * 8 + j]);
    } else if (idx < 393216) {               // w2f: 16rt x 16ks plain (K=512)
        int e = idx - 262144;
        int j = e & 7, lane = (e >> 3) & 63, rs = e >> 9;
        int ks = rs & 15, rt = rs >> 4;
        w2f[e] = cvt(w2[(rt * 16 + (lane & 15)) * 512 + ks * 32 + (lane >> 4) * 8 + j]);
    } else if (idx < 409600) {               // Kf: [h][mt] B-frag: B[d][m]=K[d*8+h][m]
        int e = idx - 393216;
        int j = e & 7, lane = (e >> 3) & 63, hm = e >> 9;
        int mt = hm & 3, h = hm >> 2;
        int d = (lane >> 4) * 8 + j, m = mt * 16 + (lane & 15);
        Kf[e] = cvt(Kf32[(d * 8 + h) * 64 + m]);
    } else if (idx < 425984) {               // Vf: [h][rt][ks] A-frag: A[d][m]=V[d*8+h][m]
        int e = idx - 409600;
        int j = e & 7, lane = (e >> 3) & 63, x = e >> 9;
        int ks = x & 1, rt = (x >> 1) & 1, h = x >> 2;
        int d = rt * 16 + (lane & 15), m = ks * 32 + (lane >> 4) * 8 + j;
        Vf[e] = cvt(Vf32[(d * 8 + h) * 64 + m]);
    } else if (idx < 426240) {               // bqp
        int op = idx - 425984;
        int c = (op & 31) * 8 + (op >> 5);
        bqp[op] = bq[c];
    }
}

// ---------------------------------------------------------------------------
// Fused SFTA with MFMA. One block per (batch, 64-col n-tile).
// NEW partition: wave w owns OUTPUT-CHANNEL band [w*64, w*64+64) (= 4 MFMA
// row-tiles = heads 2w,2w+1) and loops over all four 16-row n-groups. Each
// weight fragment is loaded from L2 ONCE per block and reused 4x in registers
// (was: once per MFMA, 4 waves redundantly -> 4x the traffic).
// ---------------------------------------------------------------------------
__global__ __launch_bounds__(256, 2) void sfta_mfma(
    const float* __restrict__ feat,
    const bf16_t* __restrict__ wqf, const float* __restrict__ bqp,
    const bf16_t* __restrict__ wmf, const float* __restrict__ bm,
    const bf16_t* __restrict__ w1f, const float* __restrict__ b1,
    const bf16_t* __restrict__ w2f, const float* __restrict__ b2,
    const bf16_t* __restrict__ Kf,  const bf16_t* __restrict__ Vf,
    const float* __restrict__ gam,  const float* __restrict__ bet,
    float* __restrict__ out) {
    // stride 264 (mult of 8 -> 16B-aligned rows, 2-way max bank aliasing = free)
    __shared__ __align__(16) bf16_t sFeat[64 * 264];   // [n][c] feat -> rescaled out
    __shared__ __align__(16) bf16_t sQX[64 * 264];     // [n][hd]: q -> x -> h1 chunk
    __shared__ __align__(16) bf16_t sP[4][16 * 72];    // per-wave prob staging
    __shared__ float sRed[3][4][64];                   // cross-wave partials [stat][band][row]

    const int t    = threadIdx.x;
    const int wid  = t >> 6;          // channel band / head-pair owner
    const int lane = t & 63;
    const int quad = lane >> 4;
    const int lid  = lane & 15;
    const int b    = blockIdx.y;
    const int n0   = blockIdx.x * NTILE;
    const size_t baseF = (size_t)b * Cc * Nn + n0;
    const int rbase = wid * 4;        // this wave's rt base (out-channels rbase*16..+64)

    // ---- stage feature tile: global [c][n] fp32 -> LDS [n][c] bf16 ----
    {
        int cb = t >> 4;            // 0..15
        int nb = (t & 15) * 4;      // 0..60
        for (int i = 0; i < 16; ++i) {
            int c = i * 16 + cb;
            const float4 f4 = *(const float4*)(feat + baseF + (size_t)c * Nn + nb);
            sFeat[(nb + 0) * 264 + c] = cvt(f4.x);
            sFeat[(nb + 1) * 264 + c] = cvt(f4.y);
            sFeat[(nb + 2) * 264 + c] = cvt(f4.z);
            sFeat[(nb + 3) * 264 + c] = cvt(f4.w);
        }
    }
    __syncthreads();

    bf16_t* pw = sP[wid];

    // ---- Q projection: wave computes q channels [wid*64, +64) for ALL rows ----
    {
        f32x4 acc[4][4];            // [rt][nt]
        #pragma unroll
        for (int rt = 0; rt < 4; ++rt)
            #pragma unroll
            for (int nt = 0; nt < 4; ++nt) acc[rt][nt] = (f32x4){0.f, 0.f, 0.f, 0.f};
        #pragma unroll
        for (int ks = 0; ks < 8; ++ks) {
            bf16x8 bfr[4];
            #pragma unroll
            for (int nt = 0; nt < 4; ++nt)
                bfr[nt] = *(const bf16x8*)(sFeat + (nt * 16 + lid) * 264 + ks * 32 + quad * 8);
            #pragma unroll
            for (int rt = 0; rt < 4; ++rt) {
                bf16x8 a = *(const bf16x8*)(wqf + (((rbase + rt) * 8 + ks) * 64 + lane) * 8);
                #pragma unroll
                for (int nt = 0; nt < 4; ++nt) acc[rt][nt] = mfma16(a, bfr[nt], acc[rt][nt]);
            }
        }
        #pragma unroll
        for (int rt = 0; rt < 4; ++rt) {
            int ob = (rbase + rt) * 16 + quad * 4;
            #pragma unroll
            for (int nt = 0; nt < 4; ++nt) {
                bf16x4 o;
                #pragma unroll
                for (int r = 0; r < 4; ++r) o[r] = cvt(acc[rt][nt][r] + bqp[ob + r]);
                *(bf16x4*)(sQX + (nt * 16 + lid) * 264 + ob) = o;
            }
        }
    }
    // q band is wave-private: no barrier needed before attention

    // ---- attention: wave handles heads 2*wid, 2*wid+1 over all 4 n-groups ----
    const float scl = 0.17677669529663687f;  // 1/sqrt(32)
    #pragma unroll 1
    for (int hh = 0; hh < 2; ++hh) {
        const int h = wid * 2 + hh;
        bf16x8 kb[4], va[4];
        #pragma unroll
        for (int mt = 0; mt < 4; ++mt)
            kb[mt] = *(const bf16x8*)(Kf + ((h * 4 + mt) * 64 + lane) * 8);
        #pragma unroll
        for (int rv = 0; rv < 4; ++rv)
            va[rv] = *(const bf16x8*)(Vf + ((h * 4 + rv) * 64 + lane) * 8);
        #pragma unroll 1
        for (int g = 0; g < 4; ++g) {
            bf16x8 aq = *(const bf16x8*)(sQX + (g * 16 + lid) * 264 + h * 32 + quad * 8);
            f32x4 sc[4];
            #pragma unroll
            for (int mt = 0; mt < 4; ++mt) {
                f32x4 z = {0.f, 0.f, 0.f, 0.f};
                sc[mt] = mfma16(aq, kb[mt], z);      // D[n-local][m]
            }
            float p[4][4];
            #pragma unroll
            for (int r = 0; r < 4; ++r) {            // softmax over m, row = quad*4+r
                float v0 = sc[0][r] * scl, v1 = sc[1][r] * scl;
                float v2 = sc[2][r] * scl, v3 = sc[3][r] * scl;
                float mx = fmaxf(fmaxf(v0, v1), fmaxf(v2, v3));
                mx = fmaxf(mx, __shfl_xor(mx, 1));
                mx = fmaxf(mx, __shfl_xor(mx, 2));
                mx = fmaxf(mx, __shfl_xor(mx, 4));
                mx = fmaxf(mx, __shfl_xor(mx, 8));
                v0 = __expf(v0 - mx); v1 = __expf(v1 - mx);
                v2 = __expf(v2 - mx); v3 = __expf(v3 - mx);
                float s = v0 + v1 + v2 + v3;
                s += __shfl_xor(s, 1); s += __shfl_xor(s, 2);
                s += __shfl_xor(s, 4); s += __shfl_xor(s, 8);
                float inv = 1.f / s;
                p[0][r] = v0 * inv; p[1][r] = v1 * inv;
                p[2][r] = v2 * inv; p[3][r] = v3 * inv;
            }
            #pragma unroll
            for (int mt = 0; mt < 4; ++mt)
                #pragma unroll
                for (int r = 0; r < 4; ++r)
                    pw[(quad * 4 + r) * 72 + mt * 16 + lid] = cvt(p[mt][r]);
            #pragma unroll
            for (int rt = 0; rt < 2; ++rt) {         // PV: D[d][n]
                f32x4 x = {0.f, 0.f, 0.f, 0.f};
                #pragma unroll
                for (int ks = 0; ks < 2; ++ks) {
                    bf16x8 bp = *(const bf16x8*)(pw + lid * 72 + ks * 32 + quad * 8);
                    x = mfma16(va[rt * 2 + ks], bp, x);
                }
                int ob = h * 32 + rt * 16 + quad * 4;
                bf16x4 o;
                #pragma unroll
                for (int r = 0; r < 4; ++r) o[r] = cvt(x[r]);
                *(bf16x4*)(sQX + (g * 16 + lid) * 264 + ob) = o;   // overwrite q_h (dead)
            }
        }
    }
    __syncthreads();   // x now complete across all bands

    // ---- merge GEMM (x cross-band) + cosine partials per band ----
    float pmf[4], pmm[4], pff[4];
    {
        f32x4 acc[4][4];
        #pragma unroll
        for (int rt = 0; rt < 4; ++rt)
            #pragma unroll
            for (int nt = 0; nt < 4; ++nt) acc[rt][nt] = (f32x4){0.f, 0.f, 0.f, 0.f};
        #pragma unroll
        for (int ks = 0; ks < 8; ++ks) {
            bf16x8 bx[4];
            #pragma unroll
            for (int nt = 0; nt < 4; ++nt)
                bx[nt] = *(const bf16x8*)(sQX + (nt * 16 + lid) * 264 + ks * 32 + quad * 8);
            #pragma unroll
            for (int rt = 0; rt < 4; ++rt) {
                bf16x8 a = *(const bf16x8*)(wmf + (((rbase + rt) * 8 + ks) * 64 + lane) * 8);
                #pragma unroll
                for (int nt = 0; nt < 4; ++nt) acc[rt][nt] = mfma16(a, bx[nt], acc[rt][nt]);
            }
        }
        #pragma unroll
        for (int nt = 0; nt < 4; ++nt) { pmf[nt] = 0.f; pmm[nt] = 0.f; pff[nt] = 0.f; }
        #pragma unroll
        for (int rt = 0; rt < 4; ++rt) {
            int ob = (rbase + rt) * 16 + quad * 4;
            #pragma unroll
            for (int nt = 0; nt < 4; ++nt) {
                bf16x4 f4 = *(const bf16x4*)(sFeat + (nt * 16 + lid) * 264 + ob);
                #pragma unroll
                for (int r = 0; r < 4; ++r) {
                    float m = acc[rt][nt][r] + bm[ob + r];
                    float f = (float)f4[r];
                    pmf[nt] = fmaf(m, f, pmf[nt]);
                    pmm[nt] = fmaf(m, m, pmm[nt]);
                    pff[nt] = fmaf(f, f, pff[nt]);
                }
            }
        }
    }
    #pragma unroll
    for (int nt = 0; nt < 4; ++nt) {   // reduce over quads -> band partial per row
        pmf[nt] += __shfl_xor(pmf[nt], 16); pmf[nt] += __shfl_xor(pmf[nt], 32);
        pmm[nt] += __shfl_xor(pmm[nt], 16); pmm[nt] += __shfl_xor(pmm[nt], 32);
        pff[nt] += __shfl_xor(pff[nt], 16); pff[nt] += __shfl_xor(pff[nt], 32);
    }
    if (lane < 16) {
        #pragma unroll
        for (int nt = 0; nt < 4; ++nt) {
            sRed[0][wid][nt * 16 + lane] = pmf[nt];
            sRed[1][wid][nt * 16 + lane] = pmm[nt];
            sRed[2][wid][nt * 16 + lane] = pff[nt];
        }
    }
    __syncthreads();

    // ---- rescale feat rows wid*16..+16 in place (quad owns 64 channels) ----
    {
        int row = wid * 16 + lid;
        float smf = sRed[0][0][row] + sRed[0][1][row] + sRed[0][2][row] + sRed[0][3][row];
        float smm = sRed[1][0][row] + sRed[1][1][row] + sRed[1][2][row] + sRed[1][3][row];
        float sff = sRed[2][0][row] + sRed[2][1][row] + sRed[2][2][row] + sRed[2][3][row];
        float scale = smf / ((sqrtf(smm) + 1e-5f) * (sqrtf(sff) + 1e-5f)) + 1.f;
        bf16_t* frow = sFeat + row * 264;
        #pragma unroll
        for (int i = 0; i < 8; ++i) {
            bf16x8* pp = (bf16x8*)(frow + quad * 64 + i * 8);
            bf16x8 v = *pp;
            #pragma unroll
            for (int e = 0; e < 8; ++e) v[e] = cvt((float)v[e] * scale);
            *pp = v;
        }
    }
    __syncthreads();

    // ---- FFN: 2 chunks of 256 f-channels, h1 staged in sQX (x is dead) ----
    f32x4 acc2[4][4];
    #pragma unroll
    for (int rt = 0; rt < 4; ++rt)
        #pragma unroll
        for (int nt = 0; nt < 4; ++nt) acc2[rt][nt] = (f32x4){0.f, 0.f, 0.f, 0.f};
    #pragma unroll 1
    for (int c = 0; c < 2; ++c) {
        // FFN1: this wave computes f-rows rt1 = c*16 + rbase + rtl
        f32x4 a1[4][4];
        #pragma unroll
        for (int rtl = 0; rtl < 4; ++rtl)
            #pragma unroll
            for (int nt = 0; nt < 4; ++nt) a1[rtl][nt] = (f32x4){0.f, 0.f, 0.f, 0.f};
        #pragma unroll
        for (int ks = 0; ks < 8; ++ks) {
            bf16x8 bfr[4];
            #pragma unroll
            for (int nt = 0; nt < 4; ++nt)
                bfr[nt] = *(const bf16x8*)(sFeat + (nt * 16 + lid) * 264 + ks * 32 + quad * 8);
            #pragma unroll
            for (int rtl = 0; rtl < 4; ++rtl) {
                int rt1 = c * 16 + rbase + rtl;
                bf16x8 a = *(const bf16x8*)(w1f + ((rt1 * 8 + ks) * 64 + lane) * 8);
                #pragma unroll
                for (int nt = 0; nt < 4; ++nt) a1[rtl][nt] = mfma16(a, bfr[nt], a1[rtl][nt]);
            }
        }
        #pragma unroll
        for (int rtl = 0; rtl < 4; ++rtl) {   // relu+bias, stage h1 chunk [row][f_loc]
            int fb = (c * 16 + rbase + rtl) * 16 + quad * 4;   // global f index
            int fl = (rbase + rtl) * 16 + quad * 4;            // f_loc in chunk
            #pragma unroll
            for (int nt = 0; nt < 4; ++nt) {
                bf16x4 o;
                #pragma unroll
                for (int r = 0; r < 4; ++r) o[r] = cvt(fmaxf(a1[rtl][nt][r] + b1[fb + r], 0.f));
                *(bf16x4*)(sQX + (nt * 16 + lid) * 264 + fl) = o;
            }
        }
        __syncthreads();   // h1 chunk complete (cross-band)
        // FFN2: consume chunk, k2 = c*8 + kk
        #pragma unroll
        for (int kk = 0; kk < 8; ++kk) {
            bf16x8 bh[4];
            #pragma unroll
            for (int nt = 0; nt < 4; ++nt)
                bh[nt] = *(const bf16x8*)(sQX + (nt * 16 + lid) * 264 + kk * 32 + quad * 8);
            #pragma unroll
            for (int rt = 0; rt < 4; ++rt) {
                bf16x8 a = *(const bf16x8*)(w2f + (((rbase + rt) * 16 + c * 8 + kk) * 64 + lane) * 8);
                #pragma unroll
                for (int nt = 0; nt < 4; ++nt) acc2[rt][nt] = mfma16(a, bh[nt], acc2[rt][nt]);
            }
        }
        __syncthreads();   // chunk consumed; safe to overwrite sQX next iter
    }

    // ---- residual + LayerNorm partials ----
    float ps[4] = {0.f, 0.f, 0.f, 0.f}, pq[4] = {0.f, 0.f, 0.f, 0.f};
    #pragma unroll
    for (int rt = 0; rt < 4; ++rt) {
        int ob = (rbase + rt) * 16 + quad * 4;
        #pragma unroll
        for (int nt = 0; nt < 4; ++nt) {
            bf16x4 f4 = *(const bf16x4*)(sFeat + (nt * 16 + lid) * 264 + ob);
            #pragma unroll
            for (int r = 0; r < 4; ++r) {
                float v = acc2[rt][nt][r] + b2[ob + r] + (float)f4[r];
                acc2[rt][nt][r] = v;
                ps[nt] += v;
                pq[nt] = fmaf(v, v, pq[nt]);
            }
        }
    }
    #pragma unroll
    for (int nt = 0; nt < 4; ++nt) {
        ps[nt] += __shfl_xor(ps[nt], 16); ps[nt] += __shfl_xor(ps[nt], 32);
        pq[nt] += __shfl_xor(pq[nt], 16); pq[nt] += __shfl_xor(pq[nt], 32);
    }
    if (lane < 16) {
        #pragma unroll
        for (int nt = 0; nt < 4; ++nt) {
            sRed[0][wid][nt * 16 + lane] = ps[nt];
            sRed[1][wid][nt * 16 + lane] = pq[nt];
        }
    }
    __syncthreads();

    // ---- LayerNorm + store (band channels x all rows) ----
    float* op = out + baseF;
    #pragma unroll
    for (int nt = 0; nt < 4; ++nt) {
        int row = nt * 16 + lid;
        float s = sRed[0][0][row] + sRed[0][1][row] + sRed[0][2][row] + sRed[0][3][row];
        float q = sRed[1][0][row] + sRed[1][1][row] + sRed[1][2][row] + sRed[1][3][row];
        float mu   = s * (1.f / 256.f);
        float rstd = rsqrtf(q * (1.f / 256.f) - mu * mu + 1e-5f);
        #pragma unroll
        for (int rt = 0; rt < 4; ++rt) {
            int ob = (rbase + rt) * 16 + quad * 4;
            #pragma unroll
            for (int r = 0; r < 4; ++r) {
                float y = (acc2[rt][nt][r] - mu) * rstd * gam[ob + r] + bet[ob + r];
                op[(size_t)(ob + r) * Nn + row] = y;
            }
        }
    }
}

// ---------------------------------------------------------------------------
extern "C" void kernel_launch(void* const* d_in, const int* in_sizes, int n_in,
                              void* d_out, int out_size, void* d_ws, size_t ws_size,
                              hipStream_t stream) {
    const float* feature = (const float*)d_in[0];
    const float* bcw     = (const float*)d_in[1];
    const float* wq = (const float*)d_in[2];  const float* bq = (const float*)d_in[3];
    const float* wk = (const float*)d_in[4];  const float* bk = (const float*)d_in[5];
    const float* wv = (const float*)d_in[6];  const float* bv = (const float*)d_in[7];
    const float* wm = (const float*)d_in[8];  const float* bm = (const float*)d_in[9];
    const float* w1 = (const float*)d_in[10]; const float* b1 = (const float*)d_in[11];
    const float* w2 = (const float*)d_in[12]; const float* b2 = (const float*)d_in[13];
    const float* gm = (const float*)d_in[14]; const float* bt = (const float*)d_in[15];

    // workspace layout (~962 KB)
    float*  Kf32 = (float*)d_ws;             // 16384 f32
    float*  Vf32 = Kf32 + 16384;             // 16384 f32
    bf16_t* wqf  = (bf16_t*)(Vf32 + 16384);  // 65536 bf16
    bf16_t* wmf  = wqf + 65536;              // 65536
    bf16_t* w1f  = wmf + 65536;              // 131072
    bf16_t* w2f  = w1f + 131072;             // 131072
    bf16_t* Kf   = w2f + 131072;             // 16384
    bf16_t* Vf   = Kf + 16384;               // 16384
    float*  bqp  = (float*)(Vf + 16384);     // 256 f32

    float* op = (float*)d_out;

    hipLaunchKernelGGL(kv_kernel, dim3(Cc), dim3(Mm), 0, stream,
                       wk, bk, wv, bv, bcw, Kf32, Vf32);
    hipLaunchKernelGGL(pack_kernel, dim3((426240 + 255) / 256), dim3(256), 0, stream,
                       wq, bq, wm, w1, w2, Kf32, Vf32,
                       wqf, wmf, w1f, w2f, Kf, Vf, bqp);
    hipLaunchKernelGGL(sfta_mfma, dim3(NTB, Bc), dim3(256), 0, stream,
                       feature, wqf, bqp, wmf, bm, w1f, b1, w2f, b2,
                       Kf, Vf, gm, bt, op);
}

// Round 2
// 488.698 us; speedup vs baseline: 1.8695x; 1.0438x over previous
//
#include <hip/hip_runtime.h>

#define Bc   64
#define Cc   256
#define Nn   2304
#define DFFf 512
#define Mm   64
#define NTILE 64
#define NTB   36   // 2304/64

typedef __bf16 bf16_t;
typedef __bf16 bf16x8 __attribute__((ext_vector_type(8)));
typedef __bf16 bf16x4 __attribute__((ext_vector_type(4)));
typedef float  f32x4  __attribute__((ext_vector_type(4)));

__device__ __forceinline__ bf16_t cvt(float f) { return (bf16_t)f; }

__device__ __forceinline__ f32x4 mfma16(bf16x8 a, bf16x8 b, f32x4 c) {
    return __builtin_amdgcn_mfma_f32_16x16x32_bf16(a, b, c, 0, 0, 0);
}

// ---------------------------------------------------------------------------
// K/V precompute (fp32): K[c][m] = wk[c,:]·bcw[m,:] + bk[c]   (unchanged)
// ---------------------------------------------------------------------------
__global__ void kv_kernel(const float* __restrict__ wk, const float* __restrict__ bk,
                          const float* __restrict__ wv, const float* __restrict__ bv,
                          const float* __restrict__ bcw,
                          float* __restrict__ Kout, float* __restrict__ Vout) {
    int c = blockIdx.x;      // 256
    int m = threadIdx.x;     // 64
    const float* wkr = wk + c * Cc;
    const float* wvr = wv + c * Cc;
    const float* br  = bcw + m * Cc;
    float aK = 0.f, aV = 0.f;
    #pragma unroll 8
    for (int i = 0; i < Cc; ++i) {
        float bcv = br[i];
        aK = fmaf(wkr[i], bcv, aK);
        aV = fmaf(wvr[i], bcv, aV);
    }
    Kout[c * Mm + m] = aK + bk[c];
    Vout[c * Mm + m] = aV + bv[c];
}

// ---------------------------------------------------------------------------
// Pack weights into MFMA A-fragment order (bf16).
// NEW vs prev round: (a) wqf rows carry permuted d so the Q-proj D-layout is
// directly the B-frag for swapped scores mfma(K,q); (b) Kf m-rows permuted so
// the swapped-score D[m][n] layout packs in-lane into the PV B-frag.
// Vf/wmf/w1f/w2f unchanged.
// ---------------------------------------------------------------------------
__global__ void pack_kernel(const float* __restrict__ wq, const float* __restrict__ bq,
                            const float* __restrict__ wm, const float* __restrict__ w1,
                            const float* __restrict__ w2,
                            const float* __restrict__ Kf32, const float* __restrict__ Vf32,
                            bf16_t* __restrict__ wqf, bf16_t* __restrict__ wmf,
                            bf16_t* __restrict__ w1f, bf16_t* __restrict__ w2f,
                            bf16_t* __restrict__ Kf, bf16_t* __restrict__ Vf,
                            float* __restrict__ bqp) {
    int idx = blockIdx.x * 256 + threadIdx.x;
    if (idx < 65536) {                       // wqf: 16rt x 8ks, d-permuted rows
        int e = idx;
        int j = e & 7, lane = (e >> 3) & 63, rs = e >> 9;
        int ks = rs & 7, rt = rs >> 3;
        int rho = lane & 15;                      // frag row in tile
        int h = rt >> 1, rtl = rt & 1;
        int d = 8 * (rho >> 2) + 4 * rtl + (rho & 3);   // d-permutation
        int k  = ks * 32 + (lane >> 4) * 8 + j;
        int c  = d * 8 + h;                       // feature channel for (d,h)
        wqf[e] = cvt(wq[c * 256 + k]);
    } else if (idx < 131072) {               // wmf: col-permuted (unchanged)
        int e = idx - 65536;
        int j = e & 7, lane = (e >> 3) & 63, rs = e >> 9;
        int ks = rs & 7, rt = rs >> 3;
        int o = rt * 16 + (lane & 15);
        int k = ks * 32 + (lane >> 4) * 8 + j;    // hd
        int c = (k & 31) * 8 + (k >> 5);
        wmf[e] = cvt(wm[o * 256 + c]);
    } else if (idx < 262144) {               // w1f: 32rt x 8ks plain (unchanged)
        int e = idx - 131072;
        int j = e & 7, lane = (e >> 3) & 63, rs = e >> 9;
        int ks = rs & 7, rt = rs >> 3;
        w1f[e] = cvt(w1[(rt * 16 + (lane & 15)) * 256 + ks * 32 + (lane >> 4) * 8 + j]);
    } else if (idx < 393216) {               // w2f: 16rt x 16ks plain (unchanged)
        int e = idx - 262144;
        int j = e & 7, lane = (e >> 3) & 63, rs = e >> 9;
        int ks = rs & 15, rt = rs >> 4;
        w2f[e] = cvt(w2[(rt * 16 + (lane & 15)) * 512 + ks * 32 + (lane >> 4) * 8 + j]);
    } else if (idx < 409600) {               // Kf: [h][mt] A-frag A[m][d], m-permuted
        int e = idx - 393216;
        int j = e & 7, lane = (e >> 3) & 63, hm = e >> 9;
        int mt = hm & 3, h = hm >> 2;
        int lid = lane & 15;
        int d = (lane >> 4) * 8 + j;
        int m = 32 * (mt >> 1) + 4 * (mt & 1) + 8 * (lid >> 2) + (lid & 3);
        Kf[e] = cvt(Kf32[(d * 8 + h) * 64 + m]);
    } else if (idx < 425984) {               // Vf: [h][rt][ks] A-frag A[d][m] (unchanged)
        int e = idx - 409600;
        int j = e & 7, lane = (e >> 3) & 63, x = e >> 9;
        int ks = x & 1, rt = (x >> 1) & 1, h = x >> 2;
        int d = rt * 16 + (lane & 15), m = ks * 32 + (lane >> 4) * 8 + j;
        Vf[e] = cvt(Vf32[(d * 8 + h) * 64 + m]);
    } else if (idx < 426240) {               // bqp (hd-ordered, unchanged)
        int op = idx - 425984;
        int c = (op & 31) * 8 + (op >> 5);
        bqp[op] = bq[c];
    }
}

// ---------------------------------------------------------------------------
// Fused SFTA. 512 threads = 8 waves per block; wave w owns out-channel band
// [w*32, w*32+32) = head w, loops all four 16-row n-groups (4x weight reuse).
// Swapped-score attention: q, P never touch LDS; softmax has 2 shuffles.
// LDS 73.7 KB -> 2 blocks/CU -> 4 waves/SIMD (2x prev round).
// ---------------------------------------------------------------------------
__global__ __launch_bounds__(512, 4) void sfta_mfma(
    const float* __restrict__ feat,
    const bf16_t* __restrict__ wqf, const float* __restrict__ bqp,
    const bf16_t* __restrict__ wmf, const float* __restrict__ bm,
    const bf16_t* __restrict__ w1f, const float* __restrict__ b1,
    const bf16_t* __restrict__ w2f, const float* __restrict__ b2,
    const bf16_t* __restrict__ Kf,  const bf16_t* __restrict__ Vf,
    const float* __restrict__ gam,  const float* __restrict__ bet,
    float* __restrict__ out) {
    __shared__ __align__(16) bf16_t sFeat[64 * 264];   // [n][c] feat -> rescaled out
    __shared__ __align__(16) bf16_t sQX[64 * 264];     // [n][hd]: x, then h1 chunk
    __shared__ float sRed[3][8][64];                   // cross-wave partials

    const int t    = threadIdx.x;
    const int wid  = t >> 6;          // 0..7: head / 32-channel band owner
    const int lane = t & 63;
    const int quad = lane >> 4;
    const int lid  = lane & 15;
    const int b    = blockIdx.y;
    const int n0   = blockIdx.x * NTILE;
    const size_t baseF = (size_t)b * Cc * Nn + n0;

    // ---- stage feature tile: global [c][n] fp32 -> LDS [n][c] bf16 ----
    {
        int cb = t >> 4;            // 0..31
        int nb = (t & 15) * 4;      // 0..60
        #pragma unroll
        for (int i = 0; i < 8; ++i) {
            int c = i * 32 + cb;
            const float4 f4 = *(const float4*)(feat + baseF + (size_t)c * Nn + nb);
            sFeat[(nb + 0) * 264 + c] = cvt(f4.x);
            sFeat[(nb + 1) * 264 + c] = cvt(f4.y);
            sFeat[(nb + 2) * 264 + c] = cvt(f4.z);
            sFeat[(nb + 3) * 264 + c] = cvt(f4.w);
        }
    }
    __syncthreads();

    // ---- Q projection: wave computes its head's 32 q-channels (permuted
    //      layout: lane(quad) holds d = 8*quad + 4*rtl + r) for all 64 rows ----
    bf16x8 bq[4];                   // B-frag q[d][n] per n-group, built in-lane
    {
        f32x4 qacc[2][4];
        #pragma unroll
        for (int rtl = 0; rtl < 2; ++rtl)
            #pragma unroll
            for (int nt = 0; nt < 4; ++nt) qacc[rtl][nt] = (f32x4){0.f, 0.f, 0.f, 0.f};
        #pragma unroll
        for (int ks = 0; ks < 8; ++ks) {
            bf16x8 bfr[4];
            #pragma unroll
            for (int nt = 0; nt < 4; ++nt)
                bfr[nt] = *(const bf16x8*)(sFeat + (nt * 16 + lid) * 264 + ks * 32 + quad * 8);
            #pragma unroll
            for (int rtl = 0; rtl < 2; ++rtl) {
                bf16x8 a = *(const bf16x8*)(wqf + (((wid * 2 + rtl) * 8 + ks) * 64 + lane) * 8);
                #pragma unroll
                for (int nt = 0; nt < 4; ++nt) qacc[rtl][nt] = mfma16(a, bfr[nt], qacc[rtl][nt]);
            }
        }
        const float4 qbA = *(const float4*)(bqp + wid * 32 + quad * 8);      // rtl=0
        const float4 qbB = *(const float4*)(bqp + wid * 32 + quad * 8 + 4);  // rtl=1
        #pragma unroll
        for (int g = 0; g < 4; ++g) {
            bq[g][0] = cvt(qacc[0][g][0] + qbA.x);
            bq[g][1] = cvt(qacc[0][g][1] + qbA.y);
            bq[g][2] = cvt(qacc[0][g][2] + qbA.z);
            bq[g][3] = cvt(qacc[0][g][3] + qbA.w);
            bq[g][4] = cvt(qacc[1][g][0] + qbB.x);
            bq[g][5] = cvt(qacc[1][g][1] + qbB.y);
            bq[g][6] = cvt(qacc[1][g][2] + qbB.z);
            bq[g][7] = cvt(qacc[1][g][3] + qbB.w);
        }
    }

    // ---- attention (head = wid): scores D[m][n], in-register softmax+pack ----
    {
        bf16x8 kb[4], va[4];
        #pragma unroll
        for (int mt = 0; mt < 4; ++mt)
            kb[mt] = *(const bf16x8*)(Kf + ((wid * 4 + mt) * 64 + lane) * 8);
        #pragma unroll
        for (int rv = 0; rv < 4; ++rv)
            va[rv] = *(const bf16x8*)(Vf + ((wid * 4 + rv) * 64 + lane) * 8);
        const float scl2 = 0.17677669529663687f * 1.4426950408889634f; // /sqrt32 * log2e
        #pragma unroll 1
        for (int g = 0; g < 4; ++g) {
            f32x4 sc[4];
            #pragma unroll
            for (int mt = 0; mt < 4; ++mt) {
                f32x4 z = {0.f, 0.f, 0.f, 0.f};
                sc[mt] = mfma16(kb[mt], bq[g], z);   // D[m-perm][n=lid]
            }
            // softmax over m for column n=lid: 16 in-lane + cross-quad
            float f[16];
            #pragma unroll
            for (int mt = 0; mt < 4; ++mt)
                #pragma unroll
                for (int r = 0; r < 4; ++r) f[mt * 4 + r] = sc[mt][r] * scl2;
            float mx = f[0];
            #pragma unroll
            for (int i = 1; i < 16; ++i) mx = fmaxf(mx, f[i]);
            mx = fmaxf(mx, __shfl_xor(mx, 16));
            mx = fmaxf(mx, __shfl_xor(mx, 32));
            float s = 0.f;
            #pragma unroll
            for (int i = 0; i < 16; ++i) { f[i] = exp2f(f[i] - mx); s += f[i]; }
            s += __shfl_xor(s, 16);
            s += __shfl_xor(s, 32);
            float inv = 1.f / s;
            bf16x8 bp[2];                            // PV B-frag, pure in-lane pack
            #pragma unroll
            for (int ks = 0; ks < 2; ++ks)
                #pragma unroll
                for (int jj = 0; jj < 8; ++jj)
                    bp[ks][jj] = cvt(f[(2 * ks + (jj >> 2)) * 4 + (jj & 3)] * inv);
            #pragma unroll
            for (int rv = 0; rv < 2; ++rv) {         // PV: D[d][n]
                f32x4 x = {0.f, 0.f, 0.f, 0.f};
                x = mfma16(va[rv * 2 + 0], bp[0], x);
                x = mfma16(va[rv * 2 + 1], bp[1], x);
                bf16x4 o;
                #pragma unroll
                for (int r = 0; r < 4; ++r) o[r] = cvt(x[r]);
                *(bf16x4*)(sQX + (g * 16 + lid) * 264 + wid * 32 + rv * 16 + quad * 4) = o;
            }
        }
    }
    __syncthreads();   // x complete across all heads

    // ---- merge GEMM (x cross-band) + cosine partials per band ----
    f32x4 acc2[2][4];   // reused later as FFN2 accumulator
    float pmf[4], pmm[4], pff[4];
    {
        #pragma unroll
        for (int rtl = 0; rtl < 2; ++rtl)
            #pragma unroll
            for (int nt = 0; nt < 4; ++nt) acc2[rtl][nt] = (f32x4){0.f, 0.f, 0.f, 0.f};
        #pragma unroll
        for (int ks = 0; ks < 8; ++ks) {
            bf16x8 bx[4];
            #pragma unroll
            for (int nt = 0; nt < 4; ++nt)
                bx[nt] = *(const bf16x8*)(sQX + (nt * 16 + lid) * 264 + ks * 32 + quad * 8);
            #pragma unroll
            for (int rtl = 0; rtl < 2; ++rtl) {
                bf16x8 a = *(const bf16x8*)(wmf + (((wid * 2 + rtl) * 8 + ks) * 64 + lane) * 8);
                #pragma unroll
                for (int nt = 0; nt < 4; ++nt) acc2[rtl][nt] = mfma16(a, bx[nt], acc2[rtl][nt]);
            }
        }
        float4 bmv[2];
        bmv[0] = *(const float4*)(bm + (wid * 2 + 0) * 16 + quad * 4);
        bmv[1] = *(const float4*)(bm + (wid * 2 + 1) * 16 + quad * 4);
        #pragma unroll
        for (int nt = 0; nt < 4; ++nt) { pmf[nt] = 0.f; pmm[nt] = 0.f; pff[nt] = 0.f; }
        #pragma unroll
        for (int rtl = 0; rtl < 2; ++rtl) {
            int ob = (wid * 2 + rtl) * 16 + quad * 4;
            #pragma unroll
            for (int nt = 0; nt < 4; ++nt) {
                bf16x4 f4 = *(const bf16x4*)(sFeat + (nt * 16 + lid) * 264 + ob);
                #pragma unroll
                for (int r = 0; r < 4; ++r) {
                    float m = acc2[rtl][nt][r] + bmv[rtl][r];
                    float f = (float)f4[r];
                    pmf[nt] = fmaf(m, f, pmf[nt]);
                    pmm[nt] = fmaf(m, m, pmm[nt]);
                    pff[nt] = fmaf(f, f, pff[nt]);
                }
            }
        }
    }
    #pragma unroll
    for (int nt = 0; nt < 4; ++nt) {
        pmf[nt] += __shfl_xor(pmf[nt], 16); pmf[nt] += __shfl_xor(pmf[nt], 32);
        pmm[nt] += __shfl_xor(pmm[nt], 16); pmm[nt] += __shfl_xor(pmm[nt], 32);
        pff[nt] += __shfl_xor(pff[nt], 16); pff[nt] += __shfl_xor(pff[nt], 32);
    }
    if (lane < 16) {
        #pragma unroll
        for (int nt = 0; nt < 4; ++nt) {
            sRed[0][wid][nt * 16 + lane] = pmf[nt];
            sRed[1][wid][nt * 16 + lane] = pmm[nt];
            sRed[2][wid][nt * 16 + lane] = pff[nt];
        }
    }
    __syncthreads();

    // ---- rescale feat in place: row = wid*8+(lane>>3), 32 ch per lane ----
    {
        int row = wid * 8 + (lane >> 3);
        int c0  = (lane & 7) * 32;
        float smf = 0.f, smm = 0.f, sff = 0.f;
        #pragma unroll
        for (int k = 0; k < 8; ++k) {
            smf += sRed[0][k][row];
            smm += sRed[1][k][row];
            sff += sRed[2][k][row];
        }
        float scale = smf / ((sqrtf(smm) + 1e-5f) * (sqrtf(sff) + 1e-5f)) + 1.f;
        bf16_t* frow = sFeat + row * 264 + c0;
        #pragma unroll
        for (int i = 0; i < 4; ++i) {
            bf16x8* pp = (bf16x8*)(frow + i * 8);
            bf16x8 v = *pp;
            #pragma unroll
            for (int e = 0; e < 8; ++e) v[e] = cvt((float)v[e] * scale);
            *pp = v;
        }
    }
    __syncthreads();

    // ---- FFN: 2 chunks of 256 f-channels, h1 staged in sQX (x dead) ----
    #pragma unroll
    for (int rtl = 0; rtl < 2; ++rtl)
        #pragma unroll
        for (int nt = 0; nt < 4; ++nt) acc2[rtl][nt] = (f32x4){0.f, 0.f, 0.f, 0.f};
    #pragma unroll 1
    for (int c = 0; c < 2; ++c) {
        f32x4 a1[2][4];
        #pragma unroll
        for (int rtl = 0; rtl < 2; ++rtl)
            #pragma unroll
            for (int nt = 0; nt < 4; ++nt) a1[rtl][nt] = (f32x4){0.f, 0.f, 0.f, 0.f};
        #pragma unroll
        for (int ks = 0; ks < 8; ++ks) {
            bf16x8 bfr[4];
            #pragma unroll
            for (int nt = 0; nt < 4; ++nt)
                bfr[nt] = *(const bf16x8*)(sFeat + (nt * 16 + lid) * 264 + ks * 32 + quad * 8);
            #pragma unroll
            for (int rtl = 0; rtl < 2; ++rtl) {
                int rt1 = c * 16 + wid * 2 + rtl;
                bf16x8 a = *(const bf16x8*)(w1f + ((rt1 * 8 + ks) * 64 + lane) * 8);
                #pragma unroll
                for (int nt = 0; nt < 4; ++nt) a1[rtl][nt] = mfma16(a, bfr[nt], a1[rtl][nt]);
            }
        }
        #pragma unroll
        for (int rtl = 0; rtl < 2; ++rtl) {
            int rt1 = c * 16 + wid * 2 + rtl;
            const float4 b1v = *(const float4*)(b1 + rt1 * 16 + quad * 4);
            int fl = (wid * 2 + rtl) * 16 + quad * 4;
            #pragma unroll
            for (int nt = 0; nt < 4; ++nt) {
                bf16x4 o;
                o[0] = cvt(fmaxf(a1[rtl][nt][0] + b1v.x, 0.f));
                o[1] = cvt(fmaxf(a1[rtl][nt][1] + b1v.y, 0.f));
                o[2] = cvt(fmaxf(a1[rtl][nt][2] + b1v.z, 0.f));
                o[3] = cvt(fmaxf(a1[rtl][nt][3] + b1v.w, 0.f));
                *(bf16x4*)(sQX + (nt * 16 + lid) * 264 + fl) = o;
            }
        }
        __syncthreads();   // h1 chunk complete (cross-band)
        #pragma unroll
        for (int kk = 0; kk < 8; ++kk) {
            bf16x8 bh[4];
            #pragma unroll
            for (int nt = 0; nt < 4; ++nt)
                bh[nt] = *(const bf16x8*)(sQX + (nt * 16 + lid) * 264 + kk * 32 + quad * 8);
            #pragma unroll
            for (int rtl = 0; rtl < 2; ++rtl) {
                bf16x8 a = *(const bf16x8*)(w2f + (((wid * 2 + rtl) * 16 + c * 8 + kk) * 64 + lane) * 8);
                #pragma unroll
                for (int nt = 0; nt < 4; ++nt) acc2[rtl][nt] = mfma16(a, bh[nt], acc2[rtl][nt]);
            }
        }
        __syncthreads();   // chunk consumed; safe to overwrite sQX next iter
    }

    // ---- residual + LayerNorm partials ----
    float ps[4] = {0.f, 0.f, 0.f, 0.f}, pq[4] = {0.f, 0.f, 0.f, 0.f};
    {
        float4 b2v[2];
        b2v[0] = *(const float4*)(b2 + (wid * 2 + 0) * 16 + quad * 4);
        b2v[1] = *(const float4*)(b2 + (wid * 2 + 1) * 16 + quad * 4);
        #pragma unroll
        for (int rtl = 0; rtl < 2; ++rtl) {
            int ob = (wid * 2 + rtl) * 16 + quad * 4;
            #pragma unroll
            for (int nt = 0; nt < 4; ++nt) {
                bf16x4 f4 = *(const bf16x4*)(sFeat + (nt * 16 + lid) * 264 + ob);
                #pragma unroll
                for (int r = 0; r < 4; ++r) {
                    float v = acc2[rtl][nt][r] + ((const float*)&b2v[rtl])[r] + (float)f4[r];
                    acc2[rtl][nt][r] = v;
                    ps[nt] += v;
                    pq[nt] = fmaf(v, v, pq[nt]);
                }
            }
        }
    }
    #pragma unroll
    for (int nt = 0; nt < 4; ++nt) {
        ps[nt] += __shfl_xor(ps[nt], 16); ps[nt] += __shfl_xor(ps[nt], 32);
        pq[nt] += __shfl_xor(pq[nt], 16); pq[nt] += __shfl_xor(pq[nt], 32);
    }
    if (lane < 16) {
        #pragma unroll
        for (int nt = 0; nt < 4; ++nt) {
            sRed[0][wid][nt * 16 + lane] = ps[nt];
            sRed[1][wid][nt * 16 + lane] = pq[nt];
        }
    }
    __syncthreads();

    // ---- LayerNorm + store (band channels x all rows) ----
    float* op = out + baseF;
    float4 gv[2], bv[2];
    gv[0] = *(const float4*)(gam + (wid * 2 + 0) * 16 + quad * 4);
    gv[1] = *(const float4*)(gam + (wid * 2 + 1) * 16 + quad * 4);
    bv[0] = *(const float4*)(bet + (wid * 2 + 0) * 16 + quad * 4);
    bv[1] = *(const float4*)(bet + (wid * 2 + 1) * 16 + quad * 4);
    #pragma unroll
    for (int nt = 0; nt < 4; ++nt) {
        int row = nt * 16 + lid;
        float s = 0.f, q = 0.f;
        #pragma unroll
        for (int k = 0; k < 8; ++k) { s += sRed[0][k][row]; q += sRed[1][k][row]; }
        float mu   = s * (1.f / 256.f);
        float rstd = rsqrtf(q * (1.f / 256.f) - mu * mu + 1e-5f);
        #pragma unroll
        for (int rtl = 0; rtl < 2; ++rtl) {
            int ob = (wid * 2 + rtl) * 16 + quad * 4;
            #pragma unroll
            for (int r = 0; r < 4; ++r) {
                float y = (acc2[rtl][nt][r] - mu) * rstd * ((const float*)&gv[rtl])[r]
                          + ((const float*)&bv[rtl])[r];
                op[(size_t)(ob + r) * Nn + row] = y;
            }
        }
    }
}

// ---------------------------------------------------------------------------
extern "C" void kernel_launch(void* const* d_in, const int* in_sizes, int n_in,
                              void* d_out, int out_size, void* d_ws, size_t ws_size,
                              hipStream_t stream) {
    const float* feature = (const float*)d_in[0];
    const float* bcw     = (const float*)d_in[1];
    const float* wq = (const float*)d_in[2];  const float* bq = (const float*)d_in[3];
    const float* wk = (const float*)d_in[4];  const float* bk = (const float*)d_in[5];
    const float* wv = (const float*)d_in[6];  const float* bv = (const float*)d_in[7];
    const float* wm = (const float*)d_in[8];  const float* bm = (const float*)d_in[9];
    const float* w1 = (const float*)d_in[10]; const float* b1 = (const float*)d_in[11];
    const float* w2 = (const float*)d_in[12]; const float* b2 = (const float*)d_in[13];
    const float* gm = (const float*)d_in[14]; const float* bt = (const float*)d_in[15];

    // workspace layout (~962 KB)
    float*  Kf32 = (float*)d_ws;             // 16384 f32
    float*  Vf32 = Kf32 + 16384;             // 16384 f32
    bf16_t* wqf  = (bf16_t*)(Vf32 + 16384);  // 65536 bf16
    bf16_t* wmf  = wqf + 65536;              // 65536
    bf16_t* w1f  = wmf + 65536;              // 131072
    bf16_t* w2f  = w1f + 131072;             // 131072
    bf16_t* Kf   = w2f + 131072;             // 16384
    bf16_t* Vf   = Kf + 16384;               // 16384
    float*  bqp  = (float*)(Vf + 16384);     // 256 f32

    float* op = (float*)d_out;

    hipLaunchKernelGGL(kv_kernel, dim3(Cc), dim3(Mm), 0, stream,
                       wk, bk, wv, bv, bcw, Kf32, Vf32);
    hipLaunchKernelGGL(pack_kernel, dim3((426240 + 255) / 256), dim3(256), 0, stream,
                       wq, bq, wm, w1, w2, Kf32, Vf32,
                       wqf, wmf, w1f, w2f, Kf, Vf, bqp);
    hipLaunchKernelGGL(sfta_mfma, dim3(NTB, Bc), dim3(512), 0, stream,
                       feature, wqf, bqp, wmf, bm, w1f, b1, w2f, b2,
                       Kf, Vf, gm, bt, op);
}

// Round 3
// 455.661 us; speedup vs baseline: 2.0050x; 1.0725x over previous
//
#include <hip/hip_runtime.h>

#define Bc   64
#define Cc   256
#define Nn   2304
#define DFFf 512
#define Mm   64
#define NTILE 64
#define NTB   36   // 2304/64

typedef __bf16 bf16_t;
typedef __bf16 bf16x8 __attribute__((ext_vector_type(8)));
typedef __bf16 bf16x4 __attribute__((ext_vector_type(4)));
typedef float  f32x4  __attribute__((ext_vector_type(4)));
typedef float  f32x2  __attribute__((ext_vector_type(2)));

__device__ __forceinline__ bf16_t cvt(float f) { return (bf16_t)f; }

__device__ __forceinline__ f32x4 mfma16(bf16x8 a, bf16x8 b, f32x4 c) {
    return __builtin_amdgcn_mfma_f32_16x16x32_bf16(a, b, c, 0, 0, 0);
}

// ---------------------------------------------------------------------------
// K/V precompute (fp32): K[c][m] = wk[c,:]·bcw[m,:] + bk[c]   (unchanged)
// ---------------------------------------------------------------------------
__global__ void kv_kernel(const float* __restrict__ wk, const float* __restrict__ bk,
                          const float* __restrict__ wv, const float* __restrict__ bv,
                          const float* __restrict__ bcw,
                          float* __restrict__ Kout, float* __restrict__ Vout) {
    int c = blockIdx.x;      // 256
    int m = threadIdx.x;     // 64
    const float* wkr = wk + c * Cc;
    const float* wvr = wv + c * Cc;
    const float* br  = bcw + m * Cc;
    float aK = 0.f, aV = 0.f;
    #pragma unroll 8
    for (int i = 0; i < Cc; ++i) {
        float bcv = br[i];
        aK = fmaf(wkr[i], bcv, aK);
        aV = fmaf(wvr[i], bcv, aV);
    }
    Kout[c * Mm + m] = aK + bk[c];
    Vout[c * Mm + m] = aV + bv[c];
}

// ---------------------------------------------------------------------------
// Pack weights into MFMA A-fragment order (bf16).  (identical to round 2)
// ---------------------------------------------------------------------------
__global__ void pack_kernel(const float* __restrict__ wq, const float* __restrict__ bq,
                            const float* __restrict__ wm, const float* __restrict__ w1,
                            const float* __restrict__ w2,
                            const float* __restrict__ Kf32, const float* __restrict__ Vf32,
                            bf16_t* __restrict__ wqf, bf16_t* __restrict__ wmf,
                            bf16_t* __restrict__ w1f, bf16_t* __restrict__ w2f,
                            bf16_t* __restrict__ Kf, bf16_t* __restrict__ Vf,
                            float* __restrict__ bqp) {
    int idx = blockIdx.x * 256 + threadIdx.x;
    if (idx < 65536) {                       // wqf: 16rt x 8ks, d-permuted rows
        int e = idx;
        int j = e & 7, lane = (e >> 3) & 63, rs = e >> 9;
        int ks = rs & 7, rt = rs >> 3;
        int rho = lane & 15;                      // frag row in tile
        int h = rt >> 1, rtl = rt & 1;
        int d = 8 * (rho >> 2) + 4 * rtl + (rho & 3);   // d-permutation
        int k  = ks * 32 + (lane >> 4) * 8 + j;
        int c  = d * 8 + h;                       // feature channel for (d,h)
        wqf[e] = cvt(wq[c * 256 + k]);
    } else if (idx < 131072) {               // wmf: col-permuted
        int e = idx - 65536;
        int j = e & 7, lane = (e >> 3) & 63, rs = e >> 9;
        int ks = rs & 7, rt = rs >> 3;
        int o = rt * 16 + (lane & 15);
        int k = ks * 32 + (lane >> 4) * 8 + j;    // hd
        int c = (k & 31) * 8 + (k >> 5);
        wmf[e] = cvt(wm[o * 256 + c]);
    } else if (idx < 262144) {               // w1f: 32rt x 8ks plain
        int e = idx - 131072;
        int j = e & 7, lane = (e >> 3) & 63, rs = e >> 9;
        int ks = rs & 7, rt = rs >> 3;
        w1f[e] = cvt(w1[(rt * 16 + (lane & 15)) * 256 + ks * 32 + (lane >> 4) * 8 + j]);
    } else if (idx < 393216) {               // w2f: 16rt x 16ks plain (K=512)
        int e = idx - 262144;
        int j = e & 7, lane = (e >> 3) & 63, rs = e >> 9;
        int ks = rs & 15, rt = rs >> 4;
        w2f[e] = cvt(w2[(rt * 16 + (lane & 15)) * 512 + ks * 32 + (lane >> 4) * 8 + j]);
    } else if (idx < 409600) {               // Kf: [h][mt] A-frag A[m-perm][d]
        int e = idx - 393216;
        int j = e & 7, lane = (e >> 3) & 63, hm = e >> 9;
        int mt = hm & 3, h = hm >> 2;
        int lid = lane & 15;
        int d = (lane >> 4) * 8 + j;
        int m = 32 * (mt >> 1) + 4 * (mt & 1) + 8 * (lid >> 2) + (lid & 3);
        Kf[e] = cvt(Kf32[(d * 8 + h) * 64 + m]);
    } else if (idx < 425984) {               // Vf: [h][rt][ks] A-frag A[d][m]
        int e = idx - 409600;
        int j = e & 7, lane = (e >> 3) & 63, x = e >> 9;
        int ks = x & 1, rt = (x >> 1) & 1, h = x >> 2;
        int d = rt * 16 + (lane & 15), m = ks * 32 + (lane >> 4) * 8 + j;
        Vf[e] = cvt(Vf32[(d * 8 + h) * 64 + m]);
    } else if (idx < 426240) {               // bqp (hd-ordered)
        int op = idx - 425984;
        int c = (op & 31) * 8 + (op >> 5);
        bqp[op] = bq[c];
    }
}

// ---------------------------------------------------------------------------
// Fused SFTA. 1024 threads = 16 waves; wave w owns out-channel tile rt = w
// (16 channels) = head w>>1's d-half (rtl = w&1), loops all four 16-row
// n-groups. 2 blocks/CU x 16 waves = 32 waves/CU (100% occupancy cap).
// Staging is c-minor per 16-lane group (conflict-light transpose writes).
// ---------------------------------------------------------------------------
__global__ __launch_bounds__(1024, 8) void sfta_mfma(
    const float* __restrict__ feat,
    const bf16_t* __restrict__ wqf, const float* __restrict__ bqp,
    const bf16_t* __restrict__ wmf, const float* __restrict__ bm,
    const bf16_t* __restrict__ w1f, const float* __restrict__ b1,
    const bf16_t* __restrict__ w2f, const float* __restrict__ b2,
    const bf16_t* __restrict__ Kf,  const bf16_t* __restrict__ Vf,
    const float* __restrict__ gam,  const float* __restrict__ bet,
    float* __restrict__ out) {
    __shared__ __align__(16) bf16_t sFeat[64 * 264];   // [n][c] feat -> rescaled
    __shared__ __align__(16) bf16_t sQX[64 * 264];     // [n][hd]: q -> x -> h1
    __shared__ float sRed[3][64][18];                  // cross-wave row partials

    const int t    = threadIdx.x;
    const int wid  = t >> 6;          // 0..15: rt owner
    const int lane = t & 63;
    const int quad = lane >> 4;
    const int lid  = lane & 15;
    const int h    = wid >> 1;        // head for q/attn phases
    const int rtl  = wid & 1;         // d-half within head
    const int b    = blockIdx.y;
    const int n0   = blockIdx.x * NTILE;
    const size_t baseF = (size_t)b * Cc * Nn + n0;

    // ---- stage feature tile: [c][n] fp32 -> LDS [n][c] bf16, c-minor lanes ----
    {
        int c_lo = t & 15;
        int nb   = ((t >> 4) & 15) * 4;
        int c_hi = t >> 8;             // 0..3
        #pragma unroll
        for (int i = 0; i < 4; ++i) {
            int c = c_hi * 64 + i * 16 + c_lo;
            const float4 f4 = *(const float4*)(feat + baseF + (size_t)c * Nn + nb);
            sFeat[(nb + 0) * 264 + c] = cvt(f4.x);
            sFeat[(nb + 1) * 264 + c] = cvt(f4.y);
            sFeat[(nb + 2) * 264 + c] = cvt(f4.z);
            sFeat[(nb + 3) * 264 + c] = cvt(f4.w);
        }
    }
    __syncthreads();

    // ---- Q projection: wave computes rt=wid (16 q-channels, d-permuted) ----
    {
        f32x4 qacc[4];
        #pragma unroll
        for (int nt = 0; nt < 4; ++nt) qacc[nt] = (f32x4){0.f, 0.f, 0.f, 0.f};
        #pragma unroll
        for (int ks = 0; ks < 8; ++ks) {
            bf16x8 a = *(const bf16x8*)(wqf + ((wid * 8 + ks) * 64 + lane) * 8);
            #pragma unroll
            for (int nt = 0; nt < 4; ++nt) {
                bf16x8 bfr = *(const bf16x8*)(sFeat + (nt * 16 + lid) * 264 + ks * 32 + quad * 8);
                qacc[nt] = mfma16(a, bfr, qacc[nt]);
            }
        }
        const float4 qb = *(const float4*)(bqp + h * 32 + quad * 8 + rtl * 4);
        #pragma unroll
        for (int nt = 0; nt < 4; ++nt) {
            bf16x4 o;
            o[0] = cvt(qacc[nt][0] + qb.x);
            o[1] = cvt(qacc[nt][1] + qb.y);
            o[2] = cvt(qacc[nt][2] + qb.z);
            o[3] = cvt(qacc[nt][3] + qb.w);
            *(bf16x4*)(sQX + (nt * 16 + lid) * 264 + h * 32 + quad * 8 + rtl * 4) = o;
        }
    }
    __syncthreads();   // q halves combined across wave pairs

    // ---- attention: wave handles (head=h, g = rtl*2 + u) for u=0..1 ----
    {
        bf16x8 kb[4], va[4];
        #pragma unroll
        for (int mt = 0; mt < 4; ++mt)
            kb[mt] = *(const bf16x8*)(Kf + ((h * 4 + mt) * 64 + lane) * 8);
        #pragma unroll
        for (int rv = 0; rv < 4; ++rv)
            va[rv] = *(const bf16x8*)(Vf + ((h * 4 + rv) * 64 + lane) * 8);
        const float scl2 = 0.17677669529663687f * 1.4426950408889634f; // /sqrt32 * log2e
        #pragma unroll 1
        for (int u = 0; u < 2; ++u) {
            int g = rtl * 2 + u;
            bf16x8 aq = *(const bf16x8*)(sQX + (g * 16 + lid) * 264 + h * 32 + quad * 8);
            f32x4 sc[4];
            #pragma unroll
            for (int mt = 0; mt < 4; ++mt) {
                f32x4 z = {0.f, 0.f, 0.f, 0.f};
                sc[mt] = mfma16(kb[mt], aq, z);      // D[m-perm][n=lid]
            }
            float f[16];
            #pragma unroll
            for (int mt = 0; mt < 4; ++mt)
                #pragma unroll
                for (int r = 0; r < 4; ++r) f[mt * 4 + r] = sc[mt][r] * scl2;
            float mx = f[0];
            #pragma unroll
            for (int i = 1; i < 16; ++i) mx = fmaxf(mx, f[i]);
            mx = fmaxf(mx, __shfl_xor(mx, 16));
            mx = fmaxf(mx, __shfl_xor(mx, 32));
            float s = 0.f;
            #pragma unroll
            for (int i = 0; i < 16; ++i) { f[i] = exp2f(f[i] - mx); s += f[i]; }
            s += __shfl_xor(s, 16);
            s += __shfl_xor(s, 32);
            float inv = 1.f / s;
            bf16x8 bp[2];                            // PV B-frag, in-lane pack
            #pragma unroll
            for (int ks = 0; ks < 2; ++ks)
                #pragma unroll
                for (int jj = 0; jj < 8; ++jj)
                    bp[ks][jj] = cvt(f[(2 * ks + (jj >> 2)) * 4 + (jj & 3)] * inv);
            #pragma unroll
            for (int rv = 0; rv < 2; ++rv) {         // PV: D[d][n]
                f32x4 x = {0.f, 0.f, 0.f, 0.f};
                x = mfma16(va[rv * 2 + 0], bp[0], x);
                x = mfma16(va[rv * 2 + 1], bp[1], x);
                bf16x4 o;
                #pragma unroll
                for (int r = 0; r < 4; ++r) o[r] = cvt(x[r]);
                *(bf16x4*)(sQX + (g * 16 + lid) * 264 + h * 32 + rv * 16 + quad * 4) = o;
            }
        }
    }
    __syncthreads();   // x complete across all heads

    // ---- merge GEMM (rt = wid) + cosine partials ----
    float pmf[4], pmm[4], pff[4];
    {
        f32x4 acc[4];
        #pragma unroll
        for (int nt = 0; nt < 4; ++nt) acc[nt] = (f32x4){0.f, 0.f, 0.f, 0.f};
        #pragma unroll
        for (int ks = 0; ks < 8; ++ks) {
            bf16x8 a = *(const bf16x8*)(wmf + ((wid * 8 + ks) * 64 + lane) * 8);
            #pragma unroll
            for (int nt = 0; nt < 4; ++nt) {
                bf16x8 bx = *(const bf16x8*)(sQX + (nt * 16 + lid) * 264 + ks * 32 + quad * 8);
                acc[nt] = mfma16(a, bx, acc[nt]);
            }
        }
        const float4 bmv = *(const float4*)(bm + wid * 16 + quad * 4);
        #pragma unroll
        for (int nt = 0; nt < 4; ++nt) { pmf[nt] = 0.f; pmm[nt] = 0.f; pff[nt] = 0.f; }
        #pragma unroll
        for (int nt = 0; nt < 4; ++nt) {
            bf16x4 f4 = *(const bf16x4*)(sFeat + (nt * 16 + lid) * 264 + wid * 16 + quad * 4);
            #pragma unroll
            for (int r = 0; r < 4; ++r) {
                float m = acc[nt][r] + ((const float*)&bmv)[r];
                float f = (float)f4[r];
                pmf[nt] = fmaf(m, f, pmf[nt]);
                pmm[nt] = fmaf(m, m, pmm[nt]);
                pff[nt] = fmaf(f, f, pff[nt]);
            }
        }
    }
    #pragma unroll
    for (int nt = 0; nt < 4; ++nt) {
        pmf[nt] += __shfl_xor(pmf[nt], 16); pmf[nt] += __shfl_xor(pmf[nt], 32);
        pmm[nt] += __shfl_xor(pmm[nt], 16); pmm[nt] += __shfl_xor(pmm[nt], 32);
        pff[nt] += __shfl_xor(pff[nt], 16); pff[nt] += __shfl_xor(pff[nt], 32);
    }
    if (lane < 16) {
        #pragma unroll
        for (int nt = 0; nt < 4; ++nt) {
            sRed[0][nt * 16 + lane][wid] = pmf[nt];
            sRed[1][nt * 16 + lane][wid] = pmm[nt];
            sRed[2][nt * 16 + lane][wid] = pff[nt];
        }
    }
    __syncthreads();

    // ---- rescale feat in place: row = wid*4+quad, 16 ch per lane ----
    {
        int row = wid * 4 + quad;
        float smf = 0.f, smm = 0.f, sff = 0.f;
        #pragma unroll
        for (int k2 = 0; k2 < 8; ++k2) {
            f32x2 a0 = *(const f32x2*)(&sRed[0][row][k2 * 2]);
            f32x2 a1 = *(const f32x2*)(&sRed[1][row][k2 * 2]);
            f32x2 a2 = *(const f32x2*)(&sRed[2][row][k2 * 2]);
            smf += a0[0] + a0[1];
            smm += a1[0] + a1[1];
            sff += a2[0] + a2[1];
        }
        float scale = smf / ((sqrtf(smm) + 1e-5f) * (sqrtf(sff) + 1e-5f)) + 1.f;
        bf16_t* frow = sFeat + row * 264 + lid * 16;
        #pragma unroll
        for (int i = 0; i < 2; ++i) {
            bf16x8* pp = (bf16x8*)(frow + i * 8);
            bf16x8 v = *pp;
            #pragma unroll
            for (int e = 0; e < 8; ++e) v[e] = cvt((float)v[e] * scale);
            *pp = v;
        }
    }
    __syncthreads();

    // ---- FFN: 2 chunks of 256 f-channels; wave owns 1 f-tile per chunk ----
    f32x4 acc2[4];
    #pragma unroll
    for (int nt = 0; nt < 4; ++nt) acc2[nt] = (f32x4){0.f, 0.f, 0.f, 0.f};
    #pragma unroll 1
    for (int c = 0; c < 2; ++c) {
        int rt1 = c * 16 + wid;
        f32x4 a1[4];
        #pragma unroll
        for (int nt = 0; nt < 4; ++nt) a1[nt] = (f32x4){0.f, 0.f, 0.f, 0.f};
        #pragma unroll
        for (int ks = 0; ks < 8; ++ks) {
            bf16x8 a = *(const bf16x8*)(w1f + ((rt1 * 8 + ks) * 64 + lane) * 8);
            #pragma unroll
            for (int nt = 0; nt < 4; ++nt) {
                bf16x8 bfr = *(const bf16x8*)(sFeat + (nt * 16 + lid) * 264 + ks * 32 + quad * 8);
                a1[nt] = mfma16(a, bfr, a1[nt]);
            }
        }
        const float4 b1v = *(const float4*)(b1 + rt1 * 16 + quad * 4);
        #pragma unroll
        for (int nt = 0; nt < 4; ++nt) {
            bf16x4 o;
            o[0] = cvt(fmaxf(a1[nt][0] + b1v.x, 0.f));
            o[1] = cvt(fmaxf(a1[nt][1] + b1v.y, 0.f));
            o[2] = cvt(fmaxf(a1[nt][2] + b1v.z, 0.f));
            o[3] = cvt(fmaxf(a1[nt][3] + b1v.w, 0.f));
            *(bf16x4*)(sQX + (nt * 16 + lid) * 264 + wid * 16 + quad * 4) = o;
        }
        __syncthreads();   // h1 chunk complete
        #pragma unroll
        for (int kk = 0; kk < 8; ++kk) {
            bf16x8 a = *(const bf16x8*)(w2f + ((wid * 16 + c * 8 + kk) * 64 + lane) * 8);
            #pragma unroll
            for (int nt = 0; nt < 4; ++nt) {
                bf16x8 bh = *(const bf16x8*)(sQX + (nt * 16 + lid) * 264 + kk * 32 + quad * 8);
                acc2[nt] = mfma16(a, bh, acc2[nt]);
            }
        }
        __syncthreads();   // chunk consumed; safe to overwrite sQX
    }

    // ---- residual + LayerNorm partials ----
    float ps[4] = {0.f, 0.f, 0.f, 0.f}, pq[4] = {0.f, 0.f, 0.f, 0.f};
    {
        const float4 b2v = *(const float4*)(b2 + wid * 16 + quad * 4);
        #pragma unroll
        for (int nt = 0; nt < 4; ++nt) {
            bf16x4 f4 = *(const bf16x4*)(sFeat + (nt * 16 + lid) * 264 + wid * 16 + quad * 4);
            #pragma unroll
            for (int r = 0; r < 4; ++r) {
                float v = acc2[nt][r] + ((const float*)&b2v)[r] + (float)f4[r];
                acc2[nt][r] = v;
                ps[nt] += v;
                pq[nt] = fmaf(v, v, pq[nt]);
            }
        }
    }
    #pragma unroll
    for (int nt = 0; nt < 4; ++nt) {
        ps[nt] += __shfl_xor(ps[nt], 16); ps[nt] += __shfl_xor(ps[nt], 32);
        pq[nt] += __shfl_xor(pq[nt], 16); pq[nt] += __shfl_xor(pq[nt], 32);
    }
    if (lane < 16) {
        #pragma unroll
        for (int nt = 0; nt < 4; ++nt) {
            sRed[0][nt * 16 + lane][wid] = ps[nt];
            sRed[1][nt * 16 + lane][wid] = pq[nt];
        }
    }
    __syncthreads();

    // ---- LayerNorm + store (16 channels x all 64 rows per wave) ----
    float* op = out + baseF;
    const float4 gv = *(const float4*)(gam + wid * 16 + quad * 4);
    const float4 bv = *(const float4*)(bet + wid * 16 + quad * 4);
    #pragma unroll
    for (int nt = 0; nt < 4; ++nt) {
        int row = nt * 16 + lid;
        // split the 16-col sum across quads, combine with 2 shuffles
        float s = 0.f, q = 0.f;
        #pragma unroll
        for (int k2 = 0; k2 < 2; ++k2) {
            f32x2 a0 = *(const f32x2*)(&sRed[0][row][quad * 4 + k2 * 2]);
            f32x2 a1 = *(const f32x2*)(&sRed[1][row][quad * 4 + k2 * 2]);
            s += a0[0] + a0[1];
            q += a1[0] + a1[1];
        }
        s += __shfl_xor(s, 16); s += __shfl_xor(s, 32);
        q += __shfl_xor(q, 16); q += __shfl_xor(q, 32);
        float mu   = s * (1.f / 256.f);
        float rstd = rsqrtf(q * (1.f / 256.f) - mu * mu + 1e-5f);
        int ob = wid * 16 + quad * 4;
        #pragma unroll
        for (int r = 0; r < 4; ++r) {
            float y = (acc2[nt][r] - mu) * rstd * ((const float*)&gv)[r]
                      + ((const float*)&bv)[r];
            op[(size_t)(ob + r) * Nn + row] = y;
        }
    }
}

// ---------------------------------------------------------------------------
extern "C" void kernel_launch(void* const* d_in, const int* in_sizes, int n_in,
                              void* d_out, int out_size, void* d_ws, size_t ws_size,
                              hipStream_t stream) {
    const float* feature = (const float*)d_in[0];
    const float* bcw     = (const float*)d_in[1];
    const float* wq = (const float*)d_in[2];  const float* bq = (const float*)d_in[3];
    const float* wk = (const float*)d_in[4];  const float* bk = (const float*)d_in[5];
    const float* wv = (const float*)d_in[6];  const float* bv = (const float*)d_in[7];
    const float* wm = (const float*)d_in[8];  const float* bm = (const float*)d_in[9];
    const float* w1 = (const float*)d_in[10]; const float* b1 = (const float*)d_in[11];
    const float* w2 = (const float*)d_in[12]; const float* b2 = (const float*)d_in[13];
    const float* gm = (const float*)d_in[14]; const float* bt = (const float*)d_in[15];

    // workspace layout (~962 KB)
    float*  Kf32 = (float*)d_ws;             // 16384 f32
    float*  Vf32 = Kf32 + 16384;             // 16384 f32
    bf16_t* wqf  = (bf16_t*)(Vf32 + 16384);  // 65536 bf16
    bf16_t* wmf  = wqf + 65536;              // 65536
    bf16_t* w1f  = wmf + 65536;              // 131072
    bf16_t* w2f  = w1f + 131072;             // 131072
    bf16_t* Kf   = w2f + 131072;             // 16384
    bf16_t* Vf   = Kf + 16384;               // 16384
    float*  bqp  = (float*)(Vf + 16384);     // 256 f32

    float* op = (float*)d_out;

    hipLaunchKernelGGL(kv_kernel, dim3(Cc), dim3(Mm), 0, stream,
                       wk, bk, wv, bv, bcw, Kf32, Vf32);
    hipLaunchKernelGGL(pack_kernel, dim3((426240 + 255) / 256), dim3(256), 0, stream,
                       wq, bq, wm, w1, w2, Kf32, Vf32,
                       wqf, wmf, w1f, w2f, Kf, Vf, bqp);
    hipLaunchKernelGGL(sfta_mfma, dim3(NTB, Bc), dim3(1024), 0, stream,
                       feature, wqf, bqp, wmf, bm, w1f, b1, w2f, b2,
                       Kf, Vf, gm, bt, op);
}